// Round 3
// baseline (218.002 us; speedup 1.0000x reference)
//
#include <hip/hip_runtime.h>
#include <hip/hip_bf16.h>
#include <cstddef>

// Problem constants (B, D, CL, QL) = (32, 128, 1024, 512)
#define B_  32
#define D_  128
#define CL_ 1024
#define QL_ 512

using short8  = __attribute__((ext_vector_type(8))) short;
using short4v = __attribute__((ext_vector_type(4))) short;
using float4v = __attribute__((ext_vector_type(4))) float;

__device__ __forceinline__ unsigned short f2bf(float f) {
    unsigned int u = __float_as_uint(f);
    u += 0x7FFFu + ((u >> 16) & 1u);   // RTNE
    return (unsigned short)(u >> 16);
}
__device__ __forceinline__ float bf2f(unsigned short h) {
    return __uint_as_float(((unsigned int)h) << 16);
}

// ---------------------------------------------------------------------------
// Kernel 1: Ubf[c,d] = bf16(wq + wqc*Ct); bias[c] = sum_d wc*Ct;
//           Cbf[b,d,c] = bf16(C).  W read as float4 (128B segments/row).
// ---------------------------------------------------------------------------
__global__ __launch_bounds__(256) void k_u_bias(const float* __restrict__ C,
                                                const float* __restrict__ W,
                                                unsigned short* __restrict__ U,
                                                float* __restrict__ bias,
                                                unsigned short* __restrict__ Cbf) {
    int b  = blockIdx.y;
    int c0 = blockIdx.x * 32;
    int tid = threadIdx.x;

    __shared__ float tile[128][33];
    __shared__ float bred[32][9];

    for (int pass = 0; pass < 16; ++pass) {
        int d = pass * 8 + (tid >> 5);
        int c = tid & 31;
        float v = C[((size_t)(b * D_ + d)) * CL_ + c0 + c];
        tile[d][c] = v;
        Cbf[((size_t)(b * D_ + d)) * CL_ + c0 + c] = f2bf(v);
    }
    __syncthreads();

    int tc    = tid >> 3;
    int lane8 = tid & 7;
    int c     = c0 + tc;
    size_t wbase = ((size_t)(b * CL_ + c)) * (3 * D_);
    size_t ubase = ((size_t)(b * CL_ + c)) * D_;

    float bpart = 0.f;
    #pragma unroll
    for (int i = 0; i < 4; ++i) {
        int d = i * 32 + lane8 * 4;
        float4 wq4  = *(const float4*)(W + wbase + d);
        float4 wc4  = *(const float4*)(W + wbase + D_ + d);
        float4 wqc4 = *(const float4*)(W + wbase + 2 * D_ + d);
        float ct0 = tile[d + 0][tc], ct1 = tile[d + 1][tc];
        float ct2 = tile[d + 2][tc], ct3 = tile[d + 3][tc];
        short4v u;
        u[0] = (short)f2bf(wq4.x + wqc4.x * ct0);
        u[1] = (short)f2bf(wq4.y + wqc4.y * ct1);
        u[2] = (short)f2bf(wq4.z + wqc4.z * ct2);
        u[3] = (short)f2bf(wq4.w + wqc4.w * ct3);
        *(short4v*)(U + ubase + d) = u;
        bpart += wc4.x * ct0 + wc4.y * ct1 + wc4.z * ct2 + wc4.w * ct3;
    }
    bred[tc][lane8] = bpart;
    __syncthreads();
    if (lane8 == 0) {
        float s = 0.f;
        for (int i = 0; i < 8; ++i) s += bred[tc][i];
        bias[b * CL_ + c] = s;
    }
}

// ---------------------------------------------------------------------------
// Kernel 2: Qtbf[b,q,d] = bf16(Q[b,d,q]) (LDS transpose); Qbf[b,d,q] = bf16(Q).
// ---------------------------------------------------------------------------
__global__ __launch_bounds__(256) void k_qt(const float* __restrict__ Q,
                                            unsigned short* __restrict__ Qt,
                                            unsigned short* __restrict__ Qbf) {
    int b  = blockIdx.z;
    int d0 = blockIdx.y * 64;
    int q0 = blockIdx.x * 64;
    int tid = threadIdx.x;
    __shared__ float t[64][65];
    for (int p = 0; p < 16; ++p) {
        int d = p * 4 + (tid >> 6);
        int q = tid & 63;
        float v = Q[((size_t)(b * D_ + d0 + d)) * QL_ + q0 + q];
        t[d][q] = v;
        Qbf[((size_t)(b * D_ + d0 + d)) * QL_ + q0 + q] = f2bf(v);
    }
    __syncthreads();
    for (int p = 0; p < 16; ++p) {
        int q  = p * 4 + (tid >> 6);
        int dd = tid & 63;
        Qt[((size_t)(b * QL_ + q0 + q)) * D_ + d0 + dd] = f2bf(t[dd][q]);
    }
}

// ---------------------------------------------------------------------------
// k_sgp: fused S GEMM + softmax stats + P GEMM (flash-style over c).
// Block = (b, qt): 32 q-cols x all 1024 c in 16 chunks of 64.  Per chunk:
//   S_chunk[64c x 32q] = Us·Qts^T + bias  -> Sbf (bf16, raw S)
//   row (c) stats over this block's 32 q  -> prmax/prsum[b][qt][c] partials
//   col (q) stats: running scm/scs; online-rescaled P accumulation:
//   acc_p[128d x 32q] += Cs[128d x 64c] · exp(S - scm)[32q x 64c]^T
// End: Pbf[d,q] = acc_p / scs.  pcmax/pcsum and k_gp eliminated.
// XCD swizzle: all 16 qt-blocks of batch b land on XCD b&7 so the per-b
// Ubf/Cbf slices (512 KB) stay L2-resident.
// ---------------------------------------------------------------------------
__global__ __launch_bounds__(256) void k_sgp(const unsigned short* __restrict__ Ubf,
                                             const unsigned short* __restrict__ Qtbf,
                                             const unsigned short* __restrict__ Cbf,
                                             const float* __restrict__ bias,
                                             unsigned short* __restrict__ Sbf,
                                             unsigned short* __restrict__ Pbf,
                                             float* __restrict__ prmax,
                                             float* __restrict__ prsum) {
    int i = blockIdx.x;
    int slot = i >> 3;
    int b  = (i & 7) + 8 * (slot >> 4);
    int qt = slot & 15;
    int q0 = qt * 32;

    int tid  = threadIdx.x;
    int lane = tid & 63, wave = tid >> 6;
    int wm = wave >> 1, wn = wave & 1;
    int quad = lane >> 4, l15 = lane & 15;

    __shared__ __align__(16) short Qts[32][136];  // 32 q x 128 k
    __shared__ __align__(16) short Us[64][136];   // 64 c x 128 k (per chunk)
    __shared__ __align__(16) short Cs[128][72];   // 128 d x 64 c (per chunk)
    __shared__ __align__(16) short Ps[32][72];    // 32 q x 64 c  (expS^T, per chunk)
    __shared__ float sbias[64];
    __shared__ float scm[32], scs[32], sfac[32];
    __shared__ float cmw[2][32], csw[2][32];      // [wm][q]
    __shared__ float rmw[2][64], rsw[2][64];      // [wn][c]

    // stage Qt once; init running col stats
    #pragma unroll
    for (int p = 0; p < 2; ++p) {
        int flat = tid + p * 256;
        int row = flat >> 4, col = (flat & 15) * 8;
        *(short8*)&Qts[row][col] = *(const short8*)(Qtbf + ((size_t)(b * QL_ + q0 + row)) * D_ + col);
    }
    if (tid < 32) { scm[tid] = -1e30f; scs[tid] = 0.f; }

    const unsigned short* Ub = Ubf + (size_t)b * CL_ * D_;
    const unsigned short* Cb = Cbf + (size_t)b * D_ * CL_;

    int q_loc = wn * 16 + l15;
    float4v acc_p[4] = {};

    for (int ch = 0; ch < 16; ++ch) {
        int c0 = ch * 64;
        __syncthreads();   // protect Us/Cs/Ps vs prev P-GEMM; orders Qts/scm init
        #pragma unroll
        for (int p = 0; p < 4; ++p) {
            int flat = tid + p * 256;
            int row = flat >> 4, col = (flat & 15) * 8;
            *(short8*)&Us[row][col] = *(const short8*)(Ub + (size_t)(c0 + row) * D_ + col);
        }
        #pragma unroll
        for (int p = 0; p < 4; ++p) {
            int flat = tid + p * 256;
            int row = flat >> 3, col = (flat & 7) * 8;
            *(short8*)&Cs[row][col] = *(const short8*)(Cb + (size_t)row * CL_ + c0 + col);
        }
        if (tid < 64) sbias[tid] = bias[b * CL_ + c0 + tid];
        __syncthreads();

        // ---- S GEMM: 64c x 32q, K=128 ----
        float4v acc_s[2] = {};
        #pragma unroll
        for (int ks = 0; ks < 128; ks += 32) {
            short8 bq = *(const short8*)&Qts[q_loc][ks + quad * 8];
            short8 a0 = *(const short8*)&Us[wm * 32 + l15][ks + quad * 8];
            short8 a1 = *(const short8*)&Us[wm * 32 + 16 + l15][ks + quad * 8];
            acc_s[0] = __builtin_amdgcn_mfma_f32_16x16x32_bf16(a0, bq, acc_s[0], 0, 0, 0);
            acc_s[1] = __builtin_amdgcn_mfma_f32_16x16x32_bf16(a1, bq, acc_s[1], 0, 0, 0);
        }

        // bias + raw S store
        float v[2][4];
        #pragma unroll
        for (int fi = 0; fi < 2; ++fi)
            #pragma unroll
            for (int rr = 0; rr < 4; ++rr) {
                int c_loc = wm * 32 + fi * 16 + quad * 4 + rr;
                float x = acc_s[fi][rr] + sbias[c_loc];
                v[fi][rr] = x;
                Sbf[((size_t)(b * CL_ + c0 + c_loc)) * QL_ + q0 + q_loc] = f2bf(x);
            }

        // ---- row (c) stats over 32 q: max-then-sum butterflies over l15 ----
        float rm[2][4], rs[2][4];
        #pragma unroll
        for (int fi = 0; fi < 2; ++fi)
            #pragma unroll
            for (int rr = 0; rr < 4; ++rr) rm[fi][rr] = v[fi][rr];
        #pragma unroll
        for (int off = 1; off <= 8; off <<= 1)
            #pragma unroll
            for (int fi = 0; fi < 2; ++fi)
                #pragma unroll
                for (int rr = 0; rr < 4; ++rr)
                    rm[fi][rr] = fmaxf(rm[fi][rr], __shfl_xor(rm[fi][rr], off));
        #pragma unroll
        for (int fi = 0; fi < 2; ++fi)
            #pragma unroll
            for (int rr = 0; rr < 4; ++rr) rs[fi][rr] = __expf(v[fi][rr] - rm[fi][rr]);
        #pragma unroll
        for (int off = 1; off <= 8; off <<= 1)
            #pragma unroll
            for (int fi = 0; fi < 2; ++fi)
                #pragma unroll
                for (int rr = 0; rr < 4; ++rr)
                    rs[fi][rr] += __shfl_xor(rs[fi][rr], off);
        if (l15 == 0) {
            #pragma unroll
            for (int fi = 0; fi < 2; ++fi)
                #pragma unroll
                for (int rr = 0; rr < 4; ++rr) {
                    int c_loc = wm * 32 + fi * 16 + quad * 4 + rr;
                    rmw[wn][c_loc] = rm[fi][rr];
                    rsw[wn][c_loc] = rs[fi][rr];
                }
        }

        // ---- col (q) partials over this wm's 32 c ----
        float cm = v[0][0];
        #pragma unroll
        for (int fi = 0; fi < 2; ++fi)
            #pragma unroll
            for (int rr = 0; rr < 4; ++rr) cm = fmaxf(cm, v[fi][rr]);
        float cs = 0.f;
        #pragma unroll
        for (int fi = 0; fi < 2; ++fi)
            #pragma unroll
            for (int rr = 0; rr < 4; ++rr) cs += __expf(v[fi][rr] - cm);
        #pragma unroll
        for (int off = 16; off <= 32; off <<= 1) {
            float om = __shfl_xor(cm, off);
            float os = __shfl_xor(cs, off);
            float nm = fmaxf(cm, om);
            cs = cs * __expf(cm - nm) + os * __expf(om - nm);
            cm = nm;
        }
        if (quad == 0) { cmw[wm][q_loc] = cm; csw[wm][q_loc] = cs; }
        __syncthreads();

        if (tid < 64) {   // row merge across wn + partial write
            float m0 = rmw[0][tid], m1 = rmw[1][tid];
            float nm = fmaxf(m0, m1);
            float ss = rsw[0][tid] * __expf(m0 - nm) + rsw[1][tid] * __expf(m1 - nm);
            prmax[((size_t)(b * 16 + qt)) * CL_ + c0 + tid] = nm;
            prsum[((size_t)(b * 16 + qt)) * CL_ + c0 + tid] = ss;
        }
        if (tid < 32) {   // col merge across wm + running update
            float m0 = cmw[0][tid], m1 = cmw[1][tid];
            float mm = fmaxf(m0, m1);
            float ss = csw[0][tid] * __expf(m0 - mm) + csw[1][tid] * __expf(m1 - mm);
            float om = scm[tid];
            float nm = fmaxf(om, mm);
            float f  = __expf(om - nm);
            sfac[tid] = f;
            scs[tid] = scs[tid] * f + ss * __expf(mm - nm);
            scm[tid] = nm;
        }
        __syncthreads();

        // ---- rescale P acc; write expS^T tile ----
        float f = sfac[q_loc];
        float cmn = scm[q_loc];
        #pragma unroll
        for (int fi = 0; fi < 4; ++fi) acc_p[fi] *= f;
        #pragma unroll
        for (int fi = 0; fi < 2; ++fi)
            #pragma unroll
            for (int rr = 0; rr < 4; ++rr) {
                int c_loc = wm * 32 + fi * 16 + quad * 4 + rr;
                Ps[q_loc][c_loc] = (short)f2bf(__expf(v[fi][rr] - cmn));
            }
        __syncthreads();

        // ---- P GEMM: 128d x 32q, K=64 (this chunk's c) ----
        #pragma unroll
        for (int ks = 0; ks < 64; ks += 32) {
            short8 bp = *(const short8*)&Ps[q_loc][ks + quad * 8];
            #pragma unroll
            for (int fi = 0; fi < 4; ++fi) {
                short8 a = *(const short8*)&Cs[wm * 64 + fi * 16 + l15][ks + quad * 8];
                acc_p[fi] = __builtin_amdgcn_mfma_f32_16x16x32_bf16(a, bp, acc_p[fi], 0, 0, 0);
            }
        }
    }

    // epilogue: P = acc_p / colsum
    float sci = 1.0f / scs[q_loc];
    #pragma unroll
    for (int fi = 0; fi < 4; ++fi)
        #pragma unroll
        for (int rr = 0; rr < 4; ++rr) {
            int d = wm * 64 + fi * 16 + quad * 4 + rr;
            Pbf[((size_t)(b * D_ + d)) * QL_ + q0 + q_loc] = f2bf(acc_p[fi][rr] * sci);
        }
}

// ---------------------------------------------------------------------------
// k_av2: fused AV GEMMs.  Out[d,c] planes 0..3 in ONE pass.
//   accQ[d,c] = sum_q Qbf[d,q]*S1[c,q]   -> planes 0 (Ct), 1 (A), 2 (Ct*A)
//   accP[d,c] = sum_q Pbf[d,q]*S1[c,q]   -> plane 3 (Ct*Bm)
// Row-stat partials (prmax/prsum over 16 qt) reduced in a 64-thread prologue.
// Same XCD swizzle as k_sgp (per-b Qbf/Pbf slices L2-resident).
// ---------------------------------------------------------------------------
__global__ __launch_bounds__(256) void k_av2(const unsigned short* __restrict__ Qbf,
                                             const unsigned short* __restrict__ Pbf,
                                             const unsigned short* __restrict__ Sbf,
                                             const float* __restrict__ prmax,
                                             const float* __restrict__ prsum,
                                             const float* __restrict__ C,
                                             float* __restrict__ out) {
    int i = blockIdx.x;
    int slot = i >> 3;
    int b  = (i & 7) + 8 * (slot >> 4);
    int n0 = (slot & 15) * 64;

    int tid  = threadIdx.x;
    int lane = tid & 63, wave = tid >> 6;
    int wm = wave >> 1, wn = wave & 1;
    int quad = lane >> 4, l15 = lane & 15;

    __shared__ __align__(16) short AsQ[128][72];
    __shared__ __align__(16) short AsP[128][72];
    __shared__ __align__(16) short Bs[64][72];
    __shared__ float srm[64], sri[64];

    if (tid < 64) {
        float M = -1e30f, S = 0.f;
        #pragma unroll
        for (int qt = 0; qt < 16; ++qt) {
            float m = prmax[((size_t)(b * 16 + qt)) * CL_ + n0 + tid];
            float s = prsum[((size_t)(b * 16 + qt)) * CL_ + n0 + tid];
            float nM = fmaxf(M, m);
            S = S * __expf(M - nM) + s * __expf(m - nM);
            M = nM;
        }
        srm[tid] = M;
        sri[tid] = 1.0f / S;
    }
    __syncthreads();

    const unsigned short* Qb = Qbf + (size_t)b * D_ * QL_;
    const unsigned short* Pb = Pbf + (size_t)b * D_ * QL_;
    const unsigned short* Sb = Sbf + ((size_t)(b * CL_ + n0)) * QL_;

    int arow = tid >> 3;
    int acol = (tid & 7) * 8;
    int brow = tid >> 2;             // 0..63 (c-local row of S1)
    int bcol = (tid & 3) * 16;       // 16 k-elems per thread
    float brm = srm[brow], bri = sri[brow];

    float4v accQ[4][2] = {};
    float4v accP[4][2] = {};

    for (int k0 = 0; k0 < QL_; k0 += 64) {
        #pragma unroll
        for (int p = 0; p < 4; ++p) {
            int row = p * 32 + arow;
            *(short8*)&AsQ[row][acol] = *(const short8*)(Qb + (size_t)row * QL_ + k0 + acol);
            *(short8*)&AsP[row][acol] = *(const short8*)(Pb + (size_t)row * QL_ + k0 + acol);
        }
        #pragma unroll
        for (int h = 0; h < 2; ++h) {
            uint4 raw = *(const uint4*)(Sb + (size_t)brow * QL_ + k0 + bcol + h * 8);
            unsigned int rw[4] = {raw.x, raw.y, raw.z, raw.w};
            short8 vv;
            #pragma unroll
            for (int j = 0; j < 8; ++j) {
                unsigned short bits = (unsigned short)((rw[j >> 1] >> ((j & 1) * 16)) & 0xFFFF);
                vv[j] = (short)f2bf(__expf(bf2f(bits) - brm) * bri);
            }
            *(short8*)&Bs[brow][bcol + h * 8] = vv;
        }
        __syncthreads();
        #pragma unroll
        for (int ks = 0; ks < 64; ks += 32) {
            short8 b0 = *(const short8*)&Bs[wn * 32 + l15][ks + quad * 8];
            short8 b1 = *(const short8*)&Bs[wn * 32 + 16 + l15][ks + quad * 8];
            #pragma unroll
            for (int fi = 0; fi < 4; ++fi) {
                short8 aq = *(const short8*)&AsQ[wm * 64 + fi * 16 + l15][ks + quad * 8];
                accQ[fi][0] = __builtin_amdgcn_mfma_f32_16x16x32_bf16(aq, b0, accQ[fi][0], 0, 0, 0);
                accQ[fi][1] = __builtin_amdgcn_mfma_f32_16x16x32_bf16(aq, b1, accQ[fi][1], 0, 0, 0);
            }
            #pragma unroll
            for (int fi = 0; fi < 4; ++fi) {
                short8 ap = *(const short8*)&AsP[wm * 64 + fi * 16 + l15][ks + quad * 8];
                accP[fi][0] = __builtin_amdgcn_mfma_f32_16x16x32_bf16(ap, b0, accP[fi][0], 0, 0, 0);
                accP[fi][1] = __builtin_amdgcn_mfma_f32_16x16x32_bf16(ap, b1, accP[fi][1], 0, 0, 0);
            }
        }
        __syncthreads();
    }

    #pragma unroll
    for (int fi = 0; fi < 4; ++fi)
        #pragma unroll
        for (int fj = 0; fj < 2; ++fj)
            #pragma unroll
            for (int rr = 0; rr < 4; ++rr) {
                int d = wm * 64 + fi * 16 + quad * 4 + rr;
                int c = n0 + wn * 32 + fj * 16 + l15;
                float ct = C[((size_t)(b * D_ + d)) * CL_ + c];
                float vq = accQ[fi][fj][rr];
                float vp = accP[fi][fj][rr];
                size_t ob = ((size_t)(b * 4 * D_ + d)) * CL_ + c;
                out[ob]                        = ct;
                out[ob + (size_t)D_ * CL_]     = vq;
                out[ob + 2 * (size_t)D_ * CL_] = ct * vq;
                out[ob + 3 * (size_t)D_ * CL_] = ct * vp;
            }
}

// ---------------------------------------------------------------------------
// Launch. Workspace (~67 MB): Ubf 8.4, Qtbf 4.2, Qbf 4.2, Cbf 8.4, Pbf 4.2,
// Sbf 33.6, bias 0.13, prmax/prsum 2.1 each.
// ---------------------------------------------------------------------------
extern "C" void kernel_launch(void* const* d_in, const int* in_sizes, int n_in,
                              void* d_out, int out_size, void* d_ws, size_t ws_size,
                              hipStream_t stream) {
    const float* C = (const float*)d_in[0];
    const float* Q = (const float*)d_in[1];
    const float* W = (const float*)d_in[2];
    float* out = (float*)d_out;

    unsigned short* Ubf  = (unsigned short*)d_ws;
    unsigned short* Qtbf = Ubf  + (size_t)B_ * CL_ * D_;
    unsigned short* Qbf  = Qtbf + (size_t)B_ * QL_ * D_;
    unsigned short* Cbf  = Qbf  + (size_t)B_ * D_ * QL_;
    unsigned short* Pbf  = Cbf  + (size_t)B_ * D_ * CL_;
    unsigned short* Sbf  = Pbf  + (size_t)B_ * D_ * QL_;
    float* bias  = (float*)(Sbf + (size_t)B_ * CL_ * QL_);
    float* prmax = bias  + (size_t)B_ * CL_;
    float* prsum = prmax + (size_t)B_ * 16 * CL_;

    k_u_bias<<<dim3(CL_ / 32, B_), 256, 0, stream>>>(C, W, Ubf, bias, Cbf);
    k_qt<<<dim3(QL_ / 64, D_ / 64, B_), 256, 0, stream>>>(Q, Qtbf, Qbf);
    k_sgp<<<512, 256, 0, stream>>>(Ubf, Qtbf, Cbf, bias, Sbf, Pbf, prmax, prsum);
    k_av2<<<512, 256, 0, stream>>>(Qbf, Pbf, Sbf, prmax, prsum, C, out);
}

// Round 4
// 195.449 us; speedup vs baseline: 1.1154x; 1.1154x over previous
//
#include <hip/hip_runtime.h>
#include <hip/hip_bf16.h>
#include <cstddef>

// Problem constants (B, D, CL, QL) = (32, 128, 1024, 512)
#define B_  32
#define D_  128
#define CL_ 1024
#define QL_ 512

using short8  = __attribute__((ext_vector_type(8))) short;
using short4v = __attribute__((ext_vector_type(4))) short;
using float4v = __attribute__((ext_vector_type(4))) float;

__device__ __forceinline__ unsigned short f2bf(float f) {
    unsigned int u = __float_as_uint(f);
    u += 0x7FFFu + ((u >> 16) & 1u);   // RTNE
    return (unsigned short)(u >> 16);
}
__device__ __forceinline__ float bf2f(unsigned short h) {
    return __uint_as_float(((unsigned int)h) << 16);
}

// XCD-aware block swizzle: 512 blocks = 32 b x 16 tiles; all 16 tiles of a
// batch land on the same XCD (wgid%8 round-robin assumption).  Bijective:
// i = 128*(b>>3) + 8*t + (b&7).
__device__ __forceinline__ void swz_bt(int i, int& b, int& t) {
    b = (i & 7) + 8 * (i >> 7);
    t = (i >> 3) & 15;
}

// ---------------------------------------------------------------------------
// Kernel 1: Ubf[c,d] = bf16(wq + wqc*Ct); bias[c] = sum_d wc*Ct;
//           Cbf[b,d,c] = bf16(C).  W read as float4 (128B segments/row).
// ---------------------------------------------------------------------------
__global__ __launch_bounds__(256) void k_u_bias(const float* __restrict__ C,
                                                const float* __restrict__ W,
                                                unsigned short* __restrict__ U,
                                                float* __restrict__ bias,
                                                unsigned short* __restrict__ Cbf) {
    int b  = blockIdx.y;
    int c0 = blockIdx.x * 32;
    int tid = threadIdx.x;

    __shared__ float tile[128][33];
    __shared__ float bred[32][9];

    for (int pass = 0; pass < 16; ++pass) {
        int d = pass * 8 + (tid >> 5);
        int c = tid & 31;
        float v = C[((size_t)(b * D_ + d)) * CL_ + c0 + c];
        tile[d][c] = v;
        Cbf[((size_t)(b * D_ + d)) * CL_ + c0 + c] = f2bf(v);
    }
    __syncthreads();

    int tc    = tid >> 3;
    int lane8 = tid & 7;
    int c     = c0 + tc;
    size_t wbase = ((size_t)(b * CL_ + c)) * (3 * D_);
    size_t ubase = ((size_t)(b * CL_ + c)) * D_;

    float bpart = 0.f;
    #pragma unroll
    for (int i = 0; i < 4; ++i) {
        int d = i * 32 + lane8 * 4;
        float4 wq4  = *(const float4*)(W + wbase + d);
        float4 wc4  = *(const float4*)(W + wbase + D_ + d);
        float4 wqc4 = *(const float4*)(W + wbase + 2 * D_ + d);
        float ct0 = tile[d + 0][tc], ct1 = tile[d + 1][tc];
        float ct2 = tile[d + 2][tc], ct3 = tile[d + 3][tc];
        short4v u;
        u[0] = (short)f2bf(wq4.x + wqc4.x * ct0);
        u[1] = (short)f2bf(wq4.y + wqc4.y * ct1);
        u[2] = (short)f2bf(wq4.z + wqc4.z * ct2);
        u[3] = (short)f2bf(wq4.w + wqc4.w * ct3);
        *(short4v*)(U + ubase + d) = u;
        bpart += wc4.x * ct0 + wc4.y * ct1 + wc4.z * ct2 + wc4.w * ct3;
    }
    bred[tc][lane8] = bpart;
    __syncthreads();
    if (lane8 == 0) {
        float s = 0.f;
        for (int i = 0; i < 8; ++i) s += bred[tc][i];
        bias[b * CL_ + c] = s;
    }
}

// ---------------------------------------------------------------------------
// Kernel 2: Qtbf[b,q,d] = bf16(Q[b,d,q]) (LDS transpose); Qbf[b,d,q] = bf16(Q).
// ---------------------------------------------------------------------------
__global__ __launch_bounds__(256) void k_qt(const float* __restrict__ Q,
                                            unsigned short* __restrict__ Qt,
                                            unsigned short* __restrict__ Qbf) {
    int b  = blockIdx.z;
    int d0 = blockIdx.y * 64;
    int q0 = blockIdx.x * 64;
    int tid = threadIdx.x;
    __shared__ float t[64][65];
    for (int p = 0; p < 16; ++p) {
        int d = p * 4 + (tid >> 6);
        int q = tid & 63;
        float v = Q[((size_t)(b * D_ + d0 + d)) * QL_ + q0 + q];
        t[d][q] = v;
        Qbf[((size_t)(b * D_ + d0 + d)) * QL_ + q0 + q] = f2bf(v);
    }
    __syncthreads();
    for (int p = 0; p < 16; ++p) {
        int q  = p * 4 + (tid >> 6);
        int dd = tid & 63;
        Qt[((size_t)(b * QL_ + q0 + q)) * D_ + d0 + dd] = f2bf(t[dd][q]);
    }
}

// ---------------------------------------------------------------------------
// k_gs2: fused S GEMM + softmax stats.
// Block = (b, mt): 64 c-rows x all 512 q, K=128, 8 n-chunks of 64.
//   - Sbf[c,q] = Ubf[c,:]·Qtbf[q,:] + bias[c]   (written per chunk)
//   - row stats (over q): online in registers across chunks -> rmax/rinv
//   - column partials (over this block's 64 c) per chunk -> pcmax/pcsum
// XCD swizzle: all 16 mt-blocks of batch b on one XCD (Qtbf slice L2-hot).
// ---------------------------------------------------------------------------
__global__ __launch_bounds__(256) void k_gs2(const unsigned short* __restrict__ Ubf,
                                             const unsigned short* __restrict__ Qtbf,
                                             const float* __restrict__ bias,
                                             unsigned short* __restrict__ Sbf,
                                             float* __restrict__ rmax,
                                             float* __restrict__ rinv,
                                             float* __restrict__ pcmax,
                                             float* __restrict__ pcsum) {
    int b, mt;
    swz_bt(blockIdx.x, b, mt);
    int m0 = mt * 64;
    int tid  = threadIdx.x;
    int lane = tid & 63, wave = tid >> 6;
    int wm = wave >> 1, wn = wave & 1;
    int quad = lane >> 4, l15 = lane & 15;

    __shared__ __align__(16) short As[64][136];   // 64 c x 128 k
    __shared__ __align__(16) short Bs[64][136];   // 64 q x 128 k (per chunk)
    __shared__ float sbias[64];
    __shared__ float rmw[2][64], rsw[2][64];      // [wn][row]
    __shared__ float cmw[2][64], csw[2][64];      // [wm][col]

    const unsigned short* Ab = Ubf  + ((size_t)(b * CL_ + m0)) * D_;
    const unsigned short* Bb = Qtbf + ((size_t)(b * QL_)) * D_;

    // stage A once (whole K)
    #pragma unroll
    for (int i = 0; i < 4; ++i) {
        int flat = tid + i * 256;
        int row = flat >> 4, col = (flat & 15) * 8;
        *(short8*)&As[row][col] = *(const short8*)(Ab + (size_t)row * D_ + col);
    }
    if (tid < 64) sbias[tid] = bias[b * CL_ + m0 + tid];

    float rm_run[2][4], rs_run[2][4];
    #pragma unroll
    for (int fi = 0; fi < 2; ++fi)
        #pragma unroll
        for (int rr = 0; rr < 4; ++rr) { rm_run[fi][rr] = -1e30f; rs_run[fi][rr] = 0.f; }

    for (int chunk = 0; chunk < 8; ++chunk) {
        __syncthreads();   // protect Bs (prev MFMA) and cmw/csw (prev merge reads)
        #pragma unroll
        for (int i = 0; i < 4; ++i) {
            int flat = tid + i * 256;
            int row = flat >> 4, col = (flat & 15) * 8;
            *(short8*)&Bs[row][col] = *(const short8*)(Bb + (size_t)(chunk * 64 + row) * D_ + col);
        }
        __syncthreads();

        float4v acc[2][2] = {};
        #pragma unroll
        for (int ks = 0; ks < 128; ks += 32) {
            short8 af0 = *(const short8*)&As[wm * 32 + l15][ks + quad * 8];
            short8 af1 = *(const short8*)&As[wm * 32 + 16 + l15][ks + quad * 8];
            short8 bf0 = *(const short8*)&Bs[wn * 32 + l15][ks + quad * 8];
            short8 bf1 = *(const short8*)&Bs[wn * 32 + 16 + l15][ks + quad * 8];
            acc[0][0] = __builtin_amdgcn_mfma_f32_16x16x32_bf16(af0, bf0, acc[0][0], 0, 0, 0);
            acc[0][1] = __builtin_amdgcn_mfma_f32_16x16x32_bf16(af0, bf1, acc[0][1], 0, 0, 0);
            acc[1][0] = __builtin_amdgcn_mfma_f32_16x16x32_bf16(af1, bf0, acc[1][0], 0, 0, 0);
            acc[1][1] = __builtin_amdgcn_mfma_f32_16x16x32_bf16(af1, bf1, acc[1][1], 0, 0, 0);
        }

        // bias + store S + stats
        float v[2][2][4];
        #pragma unroll
        for (int fi = 0; fi < 2; ++fi)
            #pragma unroll
            for (int fj = 0; fj < 2; ++fj)
                #pragma unroll
                for (int rr = 0; rr < 4; ++rr) {
                    int mloc = wm * 32 + fi * 16 + quad * 4 + rr;
                    float x = acc[fi][fj][rr] + sbias[mloc];
                    v[fi][fj][rr] = x;
                    int nloc = wn * 32 + fj * 16 + l15;
                    Sbf[((size_t)(b * CL_ + m0 + mloc)) * QL_ + chunk * 64 + nloc] = f2bf(x);
                }

        // row running update (per lane: rows (fi,rr), cols fj pair)
        #pragma unroll
        for (int fi = 0; fi < 2; ++fi)
            #pragma unroll
            for (int rr = 0; rr < 4; ++rr) {
                float v0 = v[fi][0][rr], v1 = v[fi][1][rr];
                float nm = fmaxf(rm_run[fi][rr], fmaxf(v0, v1));
                rs_run[fi][rr] = rs_run[fi][rr] * __expf(rm_run[fi][rr] - nm)
                               + __expf(v0 - nm) + __expf(v1 - nm);
                rm_run[fi][rr] = nm;
            }

        // column partials: per lane per fj over its 8 rows, then quad butterfly
        #pragma unroll
        for (int fj = 0; fj < 2; ++fj) {
            float cm = v[0][fj][0];
            #pragma unroll
            for (int fi = 0; fi < 2; ++fi)
                #pragma unroll
                for (int rr = 0; rr < 4; ++rr) cm = fmaxf(cm, v[fi][fj][rr]);
            float cs = 0.f;
            #pragma unroll
            for (int fi = 0; fi < 2; ++fi)
                #pragma unroll
                for (int rr = 0; rr < 4; ++rr) cs += __expf(v[fi][fj][rr] - cm);
            #pragma unroll
            for (int off = 16; off <= 32; off <<= 1) {
                float om = __shfl_xor(cm, off);
                float os = __shfl_xor(cs, off);
                float nm = fmaxf(cm, om);
                cs = cs * __expf(cm - nm) + os * __expf(om - nm);
                cm = nm;
            }
            if (quad == 0) {
                int col = wn * 32 + fj * 16 + l15;
                cmw[wm][col] = cm;
                csw[wm][col] = cs;
            }
        }
        __syncthreads();
        if (tid < 64) {
            float m0v = cmw[0][tid], s0v = csw[0][tid];
            float m1v = cmw[1][tid], s1v = csw[1][tid];
            float nm = fmaxf(m0v, m1v);
            float ss = s0v * __expf(m0v - nm) + s1v * __expf(m1v - nm);
            size_t pi = ((size_t)(b * 16 + mt)) * QL_ + chunk * 64 + tid;
            pcmax[pi] = nm;
            pcsum[pi] = ss;
        }
    }

    // finalize row stats: butterfly over l15, then cross-wn merge via LDS
    #pragma unroll
    for (int off = 1; off <= 8; off <<= 1)
        #pragma unroll
        for (int fi = 0; fi < 2; ++fi)
            #pragma unroll
            for (int rr = 0; rr < 4; ++rr) {
                float om = __shfl_xor(rm_run[fi][rr], off);
                float os = __shfl_xor(rs_run[fi][rr], off);
                float nm = fmaxf(rm_run[fi][rr], om);
                rs_run[fi][rr] = rs_run[fi][rr] * __expf(rm_run[fi][rr] - nm)
                               + os * __expf(om - nm);
                rm_run[fi][rr] = nm;
            }
    if (l15 == 0) {
        #pragma unroll
        for (int fi = 0; fi < 2; ++fi)
            #pragma unroll
            for (int rr = 0; rr < 4; ++rr) {
                int m = wm * 32 + fi * 16 + quad * 4 + rr;
                rmw[wn][m] = rm_run[fi][rr];
                rsw[wn][m] = rs_run[fi][rr];
            }
    }
    __syncthreads();
    if (tid < 64) {
        float m0v = rmw[0][tid], s0v = rsw[0][tid];
        float m1v = rmw[1][tid], s1v = rsw[1][tid];
        float nm = fmaxf(m0v, m1v);
        float ss = s0v * __expf(m0v - nm) + s1v * __expf(m1v - nm);
        rmax[b * CL_ + m0 + tid] = nm;
        rinv[b * CL_ + m0 + tid] = 1.0f / ss;
    }
}

// ---------------------------------------------------------------------------
// G_P: Pbf[d,q] = sum_c Cbf[d,c] * S2[c,q], S2 on-the-fly (exp + LDS transpose).
// Tile M=128 x N=32 q, K=CL, BK=64.  Column-softmax final reduce folded into a
// 32-thread prologue.  XCD swizzle: per-b Cbf slice (262 KB) L2-hot.
// ---------------------------------------------------------------------------
__global__ __launch_bounds__(256) void k_gp(const unsigned short* __restrict__ Cbf,
                                            const unsigned short* __restrict__ Sbf,
                                            const float* __restrict__ pcmax,
                                            const float* __restrict__ pcsum,
                                            unsigned short* __restrict__ Pbf) {
    int b, qt;
    swz_bt(blockIdx.x, b, qt);
    int q0 = qt * 32;

    int tid  = threadIdx.x;
    int lane = tid & 63, wave = tid >> 6;
    int quad = lane >> 4, l15 = lane & 15;

    __shared__ __align__(16) short As[128][72];
    __shared__ __align__(16) short Bs[32][72];
    __shared__ float scm[32], sci[32];

    if (tid < 32) {
        float M = -1e30f, SS = 0.f;
        #pragma unroll
        for (int ch = 0; ch < 16; ++ch) {
            size_t idx = ((size_t)(b * 16 + ch)) * QL_ + q0 + tid;
            float m = pcmax[idx], s = pcsum[idx];
            float nM = fmaxf(M, m);
            SS = SS * __expf(M - nM) + s * __expf(m - nM);
            M = nM;
        }
        scm[tid] = M;
        sci[tid] = 1.0f / SS;
    }
    __syncthreads();

    const unsigned short* Cb = Cbf + (size_t)b * D_ * CL_;
    const unsigned short* Sb = Sbf + (size_t)b * CL_ * QL_;

    int arow = tid >> 3;
    int acol = (tid & 7) * 8;
    int srow = tid >> 4;
    int uq   = tid & 15;

    float4v acc[2][2] = {};

    for (int k0 = 0; k0 < CL_; k0 += 64) {
        #pragma unroll
        for (int p = 0; p < 4; ++p) {
            int row = p * 32 + arow;
            *(short8*)&As[row][acol] = *(const short8*)(Cb + (size_t)row * CL_ + k0 + acol);
        }
        #pragma unroll
        for (int p = 0; p < 4; ++p) {
            int crow = p * 16 + srow;
            unsigned int raw = *(const unsigned int*)(Sb + (size_t)(k0 + crow) * QL_ + q0 + 2 * uq);
            float v0 = __expf(bf2f((unsigned short)(raw & 0xFFFF)) - scm[2 * uq]) * sci[2 * uq];
            float v1 = __expf(bf2f((unsigned short)(raw >> 16)) - scm[2 * uq + 1]) * sci[2 * uq + 1];
            Bs[2 * uq][crow]     = (short)f2bf(v0);
            Bs[2 * uq + 1][crow] = (short)f2bf(v1);
        }
        __syncthreads();
        #pragma unroll
        for (int ks = 0; ks < 64; ks += 32) {
            short8 a0 = *(const short8*)&As[wave * 32 + l15][ks + quad * 8];
            short8 a1 = *(const short8*)&As[wave * 32 + 16 + l15][ks + quad * 8];
            short8 b0 = *(const short8*)&Bs[l15][ks + quad * 8];
            short8 b1 = *(const short8*)&Bs[16 + l15][ks + quad * 8];
            acc[0][0] = __builtin_amdgcn_mfma_f32_16x16x32_bf16(a0, b0, acc[0][0], 0, 0, 0);
            acc[0][1] = __builtin_amdgcn_mfma_f32_16x16x32_bf16(a0, b1, acc[0][1], 0, 0, 0);
            acc[1][0] = __builtin_amdgcn_mfma_f32_16x16x32_bf16(a1, b0, acc[1][0], 0, 0, 0);
            acc[1][1] = __builtin_amdgcn_mfma_f32_16x16x32_bf16(a1, b1, acc[1][1], 0, 0, 0);
        }
        __syncthreads();
    }

    #pragma unroll
    for (int fi = 0; fi < 2; ++fi)
        #pragma unroll
        for (int fj = 0; fj < 2; ++fj)
            #pragma unroll
            for (int rr = 0; rr < 4; ++rr) {
                int d = wave * 32 + fi * 16 + quad * 4 + rr;
                int q = q0 + fj * 16 + l15;
                Pbf[((size_t)(b * D_ + d)) * QL_ + q] = f2bf(acc[fi][fj][rr]);
            }
}

// ---------------------------------------------------------------------------
// k_av2: fused AV GEMMs.  Out[d,c] planes 0..3 in ONE pass.
//   accQ[d,c] = sum_q Qbf[d,q]*S1[c,q]   -> planes 0 (Ct), 1 (A), 2 (Ct*A)
//   accP[d,c] = sum_q Pbf[d,q]*S1[c,q]   -> plane 3 (Ct*Bm)
// S1 staged into LDS ONCE per K-slab, consumed by both GEMMs.
// XCD swizzle: per-b Qbf/Pbf slices (262 KB) L2-hot.
// ---------------------------------------------------------------------------
__global__ __launch_bounds__(256) void k_av2(const unsigned short* __restrict__ Qbf,
                                             const unsigned short* __restrict__ Pbf,
                                             const unsigned short* __restrict__ Sbf,
                                             const float* __restrict__ rmax,
                                             const float* __restrict__ rinv,
                                             const float* __restrict__ C,
                                             float* __restrict__ out) {
    int b, nt;
    swz_bt(blockIdx.x, b, nt);
    int n0 = nt * 64;

    int tid  = threadIdx.x;
    int lane = tid & 63, wave = tid >> 6;
    int wm = wave >> 1, wn = wave & 1;
    int quad = lane >> 4, l15 = lane & 15;

    __shared__ __align__(16) short AsQ[128][72];
    __shared__ __align__(16) short AsP[128][72];
    __shared__ __align__(16) short Bs[64][72];
    __shared__ float srm[64], sri[64];

    if (tid < 64) {
        srm[tid] = rmax[b * CL_ + n0 + tid];
        sri[tid] = rinv[b * CL_ + n0 + tid];
    }
    __syncthreads();

    const unsigned short* Qb = Qbf + (size_t)b * D_ * QL_;
    const unsigned short* Pb = Pbf + (size_t)b * D_ * QL_;
    const unsigned short* Sb = Sbf + ((size_t)(b * CL_ + n0)) * QL_;

    int arow = tid >> 3;
    int acol = (tid & 7) * 8;
    int brow = tid >> 2;             // 0..63 (c-local row of S1)
    int bcol = (tid & 3) * 16;       // 16 k-elems per thread
    float brm = srm[brow], bri = sri[brow];

    float4v accQ[4][2] = {};
    float4v accP[4][2] = {};

    for (int k0 = 0; k0 < QL_; k0 += 64) {
        #pragma unroll
        for (int p = 0; p < 4; ++p) {
            int row = p * 32 + arow;
            *(short8*)&AsQ[row][acol] = *(const short8*)(Qb + (size_t)row * QL_ + k0 + acol);
            *(short8*)&AsP[row][acol] = *(const short8*)(Pb + (size_t)row * QL_ + k0 + acol);
        }
        #pragma unroll
        for (int h = 0; h < 2; ++h) {
            uint4 raw = *(const uint4*)(Sb + (size_t)brow * QL_ + k0 + bcol + h * 8);
            unsigned int rw[4] = {raw.x, raw.y, raw.z, raw.w};
            short8 vv;
            #pragma unroll
            for (int j = 0; j < 8; ++j) {
                unsigned short bits = (unsigned short)((rw[j >> 1] >> ((j & 1) * 16)) & 0xFFFF);
                vv[j] = (short)f2bf(__expf(bf2f(bits) - brm) * bri);
            }
            *(short8*)&Bs[brow][bcol + h * 8] = vv;
        }
        __syncthreads();
        #pragma unroll
        for (int ks = 0; ks < 64; ks += 32) {
            short8 b0 = *(const short8*)&Bs[wn * 32 + l15][ks + quad * 8];
            short8 b1 = *(const short8*)&Bs[wn * 32 + 16 + l15][ks + quad * 8];
            #pragma unroll
            for (int fi = 0; fi < 4; ++fi) {
                short8 aq = *(const short8*)&AsQ[wm * 64 + fi * 16 + l15][ks + quad * 8];
                accQ[fi][0] = __builtin_amdgcn_mfma_f32_16x16x32_bf16(aq, b0, accQ[fi][0], 0, 0, 0);
                accQ[fi][1] = __builtin_amdgcn_mfma_f32_16x16x32_bf16(aq, b1, accQ[fi][1], 0, 0, 0);
            }
            #pragma unroll
            for (int fi = 0; fi < 4; ++fi) {
                short8 ap = *(const short8*)&AsP[wm * 64 + fi * 16 + l15][ks + quad * 8];
                accP[fi][0] = __builtin_amdgcn_mfma_f32_16x16x32_bf16(ap, b0, accP[fi][0], 0, 0, 0);
                accP[fi][1] = __builtin_amdgcn_mfma_f32_16x16x32_bf16(ap, b1, accP[fi][1], 0, 0, 0);
            }
        }
        __syncthreads();
    }

    #pragma unroll
    for (int fi = 0; fi < 4; ++fi)
        #pragma unroll
        for (int fj = 0; fj < 2; ++fj)
            #pragma unroll
            for (int rr = 0; rr < 4; ++rr) {
                int d = wm * 64 + fi * 16 + quad * 4 + rr;
                int c = n0 + wn * 32 + fj * 16 + l15;
                float ct = C[((size_t)(b * D_ + d)) * CL_ + c];
                float vq = accQ[fi][fj][rr];
                float vp = accP[fi][fj][rr];
                size_t ob = ((size_t)(b * 4 * D_ + d)) * CL_ + c;
                out[ob]                        = ct;
                out[ob + (size_t)D_ * CL_]     = vq;
                out[ob + 2 * (size_t)D_ * CL_] = ct * vq;
                out[ob + 3 * (size_t)D_ * CL_] = ct * vp;
            }
}

// ---------------------------------------------------------------------------
// Launch. Workspace (~65 MB): Ubf 8.4, Qtbf 4.2, Qbf 4.2, Cbf 8.4, Pbf 4.2,
// Sbf 33.6, stats ~2.3 MB.
// ---------------------------------------------------------------------------
extern "C" void kernel_launch(void* const* d_in, const int* in_sizes, int n_in,
                              void* d_out, int out_size, void* d_ws, size_t ws_size,
                              hipStream_t stream) {
    const float* C = (const float*)d_in[0];
    const float* Q = (const float*)d_in[1];
    const float* W = (const float*)d_in[2];
    float* out = (float*)d_out;

    unsigned short* Ubf  = (unsigned short*)d_ws;
    unsigned short* Qtbf = Ubf  + (size_t)B_ * CL_ * D_;
    unsigned short* Qbf  = Qtbf + (size_t)B_ * QL_ * D_;
    unsigned short* Cbf  = Qbf  + (size_t)B_ * D_ * QL_;
    unsigned short* Pbf  = Cbf  + (size_t)B_ * D_ * CL_;
    unsigned short* Sbf  = Pbf  + (size_t)B_ * D_ * QL_;
    float* bias  = (float*)(Sbf + (size_t)B_ * CL_ * QL_);
    float* rmax  = bias  + (size_t)B_ * CL_;
    float* rinv  = rmax  + (size_t)B_ * CL_;
    float* pcmax = rinv  + (size_t)B_ * CL_;
    float* pcsum = pcmax + (size_t)B_ * 16 * QL_;

    k_u_bias<<<dim3(CL_ / 32, B_), 256, 0, stream>>>(C, W, Ubf, bias, Cbf);
    k_qt<<<dim3(QL_ / 64, D_ / 64, B_), 256, 0, stream>>>(Q, Qtbf, Qbf);
    k_gs2<<<512, 256, 0, stream>>>(Ubf, Qtbf, bias, Sbf, rmax, rinv, pcmax, pcsum);
    k_gp<<<512, 256, 0, stream>>>(Cbf, Sbf, pcmax, pcsum, Pbf);
    k_av2<<<512, 256, 0, stream>>>(Qbf, Pbf, Sbf, rmax, rinv, C, out);
}

// Round 5
// 186.259 us; speedup vs baseline: 1.1704x; 1.0493x over previous
//
#include <hip/hip_runtime.h>
#include <hip/hip_bf16.h>
#include <cstddef>

// Problem constants (B, D, CL, QL) = (32, 128, 1024, 512)
#define B_  32
#define D_  128
#define CL_ 1024
#define QL_ 512

using short8  = __attribute__((ext_vector_type(8))) short;
using short4v = __attribute__((ext_vector_type(4))) short;
using float4v = __attribute__((ext_vector_type(4))) float;

__device__ __forceinline__ unsigned short f2bf(float f) {
    unsigned int u = __float_as_uint(f);
    u += 0x7FFFu + ((u >> 16) & 1u);   // RTNE
    return (unsigned short)(u >> 16);
}
__device__ __forceinline__ float bf2f(unsigned short h) {
    return __uint_as_float(((unsigned int)h) << 16);
}

// XCD-aware block swizzle: 512 blocks = 32 b x 16 tiles; all 16 tiles of a
// batch land on the same XCD (wgid%8 round-robin assumption).  Bijective:
// i = 128*(b>>3) + 8*t + (b&7).
__device__ __forceinline__ void swz_bt(int i, int& b, int& t) {
    b = (i & 7) + 8 * (i >> 7);
    t = (i >> 3) & 15;
}

// ---------------------------------------------------------------------------
// Kernel 1: Ubf[c,d] = bf16(wq + wqc*Ct); bias[c] = sum_d wc*Ct;
//           Cbf[b,d,c] = bf16(C).  W read as float4 (128B segments/row).
// ---------------------------------------------------------------------------
__global__ __launch_bounds__(256) void k_u_bias(const float* __restrict__ C,
                                                const float* __restrict__ W,
                                                unsigned short* __restrict__ U,
                                                float* __restrict__ bias,
                                                unsigned short* __restrict__ Cbf) {
    int b  = blockIdx.y;
    int c0 = blockIdx.x * 32;
    int tid = threadIdx.x;

    __shared__ float tile[128][33];
    __shared__ float bred[32][9];

    for (int pass = 0; pass < 16; ++pass) {
        int d = pass * 8 + (tid >> 5);
        int c = tid & 31;
        float v = C[((size_t)(b * D_ + d)) * CL_ + c0 + c];
        tile[d][c] = v;
        Cbf[((size_t)(b * D_ + d)) * CL_ + c0 + c] = f2bf(v);
    }
    __syncthreads();

    int tc    = tid >> 3;
    int lane8 = tid & 7;
    int c     = c0 + tc;
    size_t wbase = ((size_t)(b * CL_ + c)) * (3 * D_);
    size_t ubase = ((size_t)(b * CL_ + c)) * D_;

    float bpart = 0.f;
    #pragma unroll
    for (int i = 0; i < 4; ++i) {
        int d = i * 32 + lane8 * 4;
        float4 wq4  = *(const float4*)(W + wbase + d);
        float4 wc4  = *(const float4*)(W + wbase + D_ + d);
        float4 wqc4 = *(const float4*)(W + wbase + 2 * D_ + d);
        float ct0 = tile[d + 0][tc], ct1 = tile[d + 1][tc];
        float ct2 = tile[d + 2][tc], ct3 = tile[d + 3][tc];
        short4v u;
        u[0] = (short)f2bf(wq4.x + wqc4.x * ct0);
        u[1] = (short)f2bf(wq4.y + wqc4.y * ct1);
        u[2] = (short)f2bf(wq4.z + wqc4.z * ct2);
        u[3] = (short)f2bf(wq4.w + wqc4.w * ct3);
        *(short4v*)(U + ubase + d) = u;
        bpart += wc4.x * ct0 + wc4.y * ct1 + wc4.z * ct2 + wc4.w * ct3;
    }
    bred[tc][lane8] = bpart;
    __syncthreads();
    if (lane8 == 0) {
        float s = 0.f;
        for (int i = 0; i < 8; ++i) s += bred[tc][i];
        bias[b * CL_ + c] = s;
    }
}

// ---------------------------------------------------------------------------
// Kernel 2: Qtbf[b,q,d] = bf16(Q[b,d,q]) (LDS transpose); Qbf[b,d,q] = bf16(Q).
// ---------------------------------------------------------------------------
__global__ __launch_bounds__(256) void k_qt(const float* __restrict__ Q,
                                            unsigned short* __restrict__ Qt,
                                            unsigned short* __restrict__ Qbf) {
    int b  = blockIdx.z;
    int d0 = blockIdx.y * 64;
    int q0 = blockIdx.x * 64;
    int tid = threadIdx.x;
    __shared__ float t[64][65];
    for (int p = 0; p < 16; ++p) {
        int d = p * 4 + (tid >> 6);
        int q = tid & 63;
        float v = Q[((size_t)(b * D_ + d0 + d)) * QL_ + q0 + q];
        t[d][q] = v;
        Qbf[((size_t)(b * D_ + d0 + d)) * QL_ + q0 + q] = f2bf(v);
    }
    __syncthreads();
    for (int p = 0; p < 16; ++p) {
        int q  = p * 4 + (tid >> 6);
        int dd = tid & 63;
        Qt[((size_t)(b * QL_ + q0 + q)) * D_ + d0 + dd] = f2bf(t[dd][q]);
    }
}

// ---------------------------------------------------------------------------
// k_gs2: fused S GEMM + softmax stats.  T3-minimum schedule:
// double-buffered Bs, register prefetch of chunk+1, ONE barrier per chunk.
// Col-partials go to chunk-indexed LDS (no per-chunk merge barrier); all
// merges in a parallel epilogue.
// ---------------------------------------------------------------------------
__global__ __launch_bounds__(256) void k_gs2(const unsigned short* __restrict__ Ubf,
                                             const unsigned short* __restrict__ Qtbf,
                                             const float* __restrict__ bias,
                                             unsigned short* __restrict__ Sbf,
                                             float* __restrict__ rmax,
                                             float* __restrict__ rinv,
                                             float* __restrict__ pcmax,
                                             float* __restrict__ pcsum) {
    int b, mt;
    swz_bt(blockIdx.x, b, mt);
    int m0 = mt * 64;
    int tid  = threadIdx.x;
    int lane = tid & 63, wave = tid >> 6;
    int wm = wave >> 1, wn = wave & 1;
    int quad = lane >> 4, l15 = lane & 15;

    __shared__ __align__(16) short As[64][136];      // 64 c x 128 k
    __shared__ __align__(16) short Bs[2][64][136];   // dbuf: 64 q x 128 k
    __shared__ float sbias[64];
    __shared__ float rmw[2][64], rsw[2][64];         // [wn][row]
    __shared__ float cmw[2][8][64], csw[2][8][64];   // [wm][chunk][col]

    const unsigned short* Ab = Ubf  + ((size_t)(b * CL_ + m0)) * D_;
    const unsigned short* Bb = Qtbf + ((size_t)(b * QL_)) * D_;

    // prologue: stage A (whole K) + Bs[0]
    #pragma unroll
    for (int i = 0; i < 4; ++i) {
        int flat = tid + i * 256;
        int row = flat >> 4, col = (flat & 15) * 8;
        *(short8*)&As[row][col]    = *(const short8*)(Ab + (size_t)row * D_ + col);
        *(short8*)&Bs[0][row][col] = *(const short8*)(Bb + (size_t)row * D_ + col);
    }
    if (tid < 64) sbias[tid] = bias[b * CL_ + m0 + tid];

    float rm_run[2][4], rs_run[2][4];
    #pragma unroll
    for (int fi = 0; fi < 2; ++fi)
        #pragma unroll
        for (int rr = 0; rr < 4; ++rr) { rm_run[fi][rr] = -1e30f; rs_run[fi][rr] = 0.f; }

    short8 pre[4];
    for (int chunk = 0; chunk < 8; ++chunk) {
        int cur = chunk & 1;
        if (chunk < 7) {   // issue next-chunk loads BEFORE the barrier/MFMA
            #pragma unroll
            for (int i = 0; i < 4; ++i) {
                int flat = tid + i * 256;
                int row = flat >> 4, col = (flat & 15) * 8;
                pre[i] = *(const short8*)(Bb + (size_t)((chunk + 1) * 64 + row) * D_ + col);
            }
        }
        __syncthreads();   // Bs[cur] writes visible; Bs[cur^1] readers done

        float4v acc[2][2] = {};
        #pragma unroll
        for (int ks = 0; ks < 128; ks += 32) {
            short8 af0 = *(const short8*)&As[wm * 32 + l15][ks + quad * 8];
            short8 af1 = *(const short8*)&As[wm * 32 + 16 + l15][ks + quad * 8];
            short8 bf0 = *(const short8*)&Bs[cur][wn * 32 + l15][ks + quad * 8];
            short8 bf1 = *(const short8*)&Bs[cur][wn * 32 + 16 + l15][ks + quad * 8];
            acc[0][0] = __builtin_amdgcn_mfma_f32_16x16x32_bf16(af0, bf0, acc[0][0], 0, 0, 0);
            acc[0][1] = __builtin_amdgcn_mfma_f32_16x16x32_bf16(af0, bf1, acc[0][1], 0, 0, 0);
            acc[1][0] = __builtin_amdgcn_mfma_f32_16x16x32_bf16(af1, bf0, acc[1][0], 0, 0, 0);
            acc[1][1] = __builtin_amdgcn_mfma_f32_16x16x32_bf16(af1, bf1, acc[1][1], 0, 0, 0);
        }

        // bias + store S + stats
        float v[2][2][4];
        #pragma unroll
        for (int fi = 0; fi < 2; ++fi)
            #pragma unroll
            for (int fj = 0; fj < 2; ++fj)
                #pragma unroll
                for (int rr = 0; rr < 4; ++rr) {
                    int mloc = wm * 32 + fi * 16 + quad * 4 + rr;
                    float x = acc[fi][fj][rr] + sbias[mloc];
                    v[fi][fj][rr] = x;
                    int nloc = wn * 32 + fj * 16 + l15;
                    Sbf[((size_t)(b * CL_ + m0 + mloc)) * QL_ + chunk * 64 + nloc] = f2bf(x);
                }

        // row running update
        #pragma unroll
        for (int fi = 0; fi < 2; ++fi)
            #pragma unroll
            for (int rr = 0; rr < 4; ++rr) {
                float v0 = v[fi][0][rr], v1 = v[fi][1][rr];
                float nm = fmaxf(rm_run[fi][rr], fmaxf(v0, v1));
                rs_run[fi][rr] = rs_run[fi][rr] * __expf(rm_run[fi][rr] - nm)
                               + __expf(v0 - nm) + __expf(v1 - nm);
                rm_run[fi][rr] = nm;
            }

        // column partials -> chunk-indexed LDS (disjoint per wave, no barrier)
        #pragma unroll
        for (int fj = 0; fj < 2; ++fj) {
            float cm = v[0][fj][0];
            #pragma unroll
            for (int fi = 0; fi < 2; ++fi)
                #pragma unroll
                for (int rr = 0; rr < 4; ++rr) cm = fmaxf(cm, v[fi][fj][rr]);
            float cs = 0.f;
            #pragma unroll
            for (int fi = 0; fi < 2; ++fi)
                #pragma unroll
                for (int rr = 0; rr < 4; ++rr) cs += __expf(v[fi][fj][rr] - cm);
            #pragma unroll
            for (int off = 16; off <= 32; off <<= 1) {
                float om = __shfl_xor(cm, off);
                float os = __shfl_xor(cs, off);
                float nm = fmaxf(cm, om);
                cs = cs * __expf(cm - nm) + os * __expf(om - nm);
                cm = nm;
            }
            if (quad == 0) {
                int col = wn * 32 + fj * 16 + l15;
                cmw[wm][chunk][col] = cm;
                csw[wm][chunk][col] = cs;
            }
        }

        if (chunk < 7) {   // write prefetched tile into the other buffer
            #pragma unroll
            for (int i = 0; i < 4; ++i) {
                int flat = tid + i * 256;
                int row = flat >> 4, col = (flat & 15) * 8;
                *(short8*)&Bs[cur ^ 1][row][col] = pre[i];
            }
        }
    }
    __syncthreads();   // cmw/csw from all waves visible

    // epilogue A: column-partial merge (8 chunks x 64 cols = 512 entries)
    #pragma unroll
    for (int e = 0; e < 2; ++e) {
        int idx = tid + e * 256;
        int ch = idx >> 6, col = idx & 63;
        float m0v = cmw[0][ch][col], m1v = cmw[1][ch][col];
        float nm = fmaxf(m0v, m1v);
        float ss = csw[0][ch][col] * __expf(m0v - nm) + csw[1][ch][col] * __expf(m1v - nm);
        size_t pi = ((size_t)(b * 16 + mt)) * QL_ + ch * 64 + col;
        pcmax[pi] = nm;
        pcsum[pi] = ss;
    }

    // epilogue B: row stats — butterfly over l15, then cross-wn merge via LDS
    #pragma unroll
    for (int off = 1; off <= 8; off <<= 1)
        #pragma unroll
        for (int fi = 0; fi < 2; ++fi)
            #pragma unroll
            for (int rr = 0; rr < 4; ++rr) {
                float om = __shfl_xor(rm_run[fi][rr], off);
                float os = __shfl_xor(rs_run[fi][rr], off);
                float nm = fmaxf(rm_run[fi][rr], om);
                rs_run[fi][rr] = rs_run[fi][rr] * __expf(rm_run[fi][rr] - nm)
                               + os * __expf(om - nm);
                rm_run[fi][rr] = nm;
            }
    if (l15 == 0) {
        #pragma unroll
        for (int fi = 0; fi < 2; ++fi)
            #pragma unroll
            for (int rr = 0; rr < 4; ++rr) {
                int m = wm * 32 + fi * 16 + quad * 4 + rr;
                rmw[wn][m] = rm_run[fi][rr];
                rsw[wn][m] = rs_run[fi][rr];
            }
    }
    __syncthreads();
    if (tid < 64) {
        float m0v = rmw[0][tid], s0v = rsw[0][tid];
        float m1v = rmw[1][tid], s1v = rsw[1][tid];
        float nm = fmaxf(m0v, m1v);
        float ss = s0v * __expf(m0v - nm) + s1v * __expf(m1v - nm);
        rmax[b * CL_ + m0 + tid] = nm;
        rinv[b * CL_ + m0 + tid] = 1.0f / ss;
    }
}

// ---------------------------------------------------------------------------
// k_gp: Pbf[d,q] = sum_c Cbf[d,c] * S2[c,q].  T3-minimum: double-buffered
// As/Bs, register prefetch, ONE barrier per K-step.
// ---------------------------------------------------------------------------
__global__ __launch_bounds__(256) void k_gp(const unsigned short* __restrict__ Cbf,
                                            const unsigned short* __restrict__ Sbf,
                                            const float* __restrict__ pcmax,
                                            const float* __restrict__ pcsum,
                                            unsigned short* __restrict__ Pbf) {
    int b, qt;
    swz_bt(blockIdx.x, b, qt);
    int q0 = qt * 32;

    int tid  = threadIdx.x;
    int lane = tid & 63, wave = tid >> 6;
    int quad = lane >> 4, l15 = lane & 15;

    __shared__ __align__(16) short As[2][128][72];
    __shared__ __align__(16) short Bs[2][32][72];
    __shared__ float scm[32], sci[32];

    const unsigned short* Cb = Cbf + (size_t)b * D_ * CL_;
    const unsigned short* Sb = Sbf + (size_t)b * CL_ * QL_;

    int arow = tid >> 3;
    int acol = (tid & 7) * 8;
    int srow = tid >> 4;
    int uq   = tid & 15;

    short8 apre[4];
    unsigned int spre[4];

    // prologue: issue step-0 loads, compute col stats, write buf 0
    #pragma unroll
    for (int p = 0; p < 4; ++p)
        apre[p] = *(const short8*)(Cb + (size_t)(p * 32 + arow) * CL_ + acol);
    #pragma unroll
    for (int p = 0; p < 4; ++p)
        spre[p] = *(const unsigned int*)(Sb + (size_t)(p * 16 + srow) * QL_ + q0 + 2 * uq);

    if (tid < 32) {
        float M = -1e30f, SS = 0.f;
        #pragma unroll
        for (int ch = 0; ch < 16; ++ch) {
            size_t idx = ((size_t)(b * 16 + ch)) * QL_ + q0 + tid;
            float m = pcmax[idx], s = pcsum[idx];
            float nM = fmaxf(M, m);
            SS = SS * __expf(M - nM) + s * __expf(m - nM);
            M = nM;
        }
        scm[tid] = M;
        sci[tid] = 1.0f / SS;
    }
    __syncthreads();   // scm/sci visible

    #pragma unroll
    for (int p = 0; p < 4; ++p)
        *(short8*)&As[0][p * 32 + arow][acol] = apre[p];
    #pragma unroll
    for (int p = 0; p < 4; ++p) {
        int crow = p * 16 + srow;
        unsigned int raw = spre[p];
        float v0 = __expf(bf2f((unsigned short)(raw & 0xFFFF)) - scm[2 * uq]) * sci[2 * uq];
        float v1 = __expf(bf2f((unsigned short)(raw >> 16)) - scm[2 * uq + 1]) * sci[2 * uq + 1];
        Bs[0][2 * uq][crow]     = (short)f2bf(v0);
        Bs[0][2 * uq + 1][crow] = (short)f2bf(v1);
    }

    float4v acc[2][2] = {};

    for (int step = 0; step < 16; ++step) {
        int cur = step & 1;
        int k0n = (step + 1) * 64;
        if (step < 15) {   // issue next-step loads before the barrier
            #pragma unroll
            for (int p = 0; p < 4; ++p)
                apre[p] = *(const short8*)(Cb + (size_t)(p * 32 + arow) * CL_ + k0n + acol);
            #pragma unroll
            for (int p = 0; p < 4; ++p)
                spre[p] = *(const unsigned int*)(Sb + (size_t)(k0n + p * 16 + srow) * QL_ + q0 + 2 * uq);
        }
        __syncthreads();   // buf[cur] writes visible; buf[cur^1] readers done

        #pragma unroll
        for (int ks = 0; ks < 64; ks += 32) {
            short8 a0 = *(const short8*)&As[cur][wave * 32 + l15][ks + quad * 8];
            short8 a1 = *(const short8*)&As[cur][wave * 32 + 16 + l15][ks + quad * 8];
            short8 b0 = *(const short8*)&Bs[cur][l15][ks + quad * 8];
            short8 b1 = *(const short8*)&Bs[cur][16 + l15][ks + quad * 8];
            acc[0][0] = __builtin_amdgcn_mfma_f32_16x16x32_bf16(a0, b0, acc[0][0], 0, 0, 0);
            acc[0][1] = __builtin_amdgcn_mfma_f32_16x16x32_bf16(a0, b1, acc[0][1], 0, 0, 0);
            acc[1][0] = __builtin_amdgcn_mfma_f32_16x16x32_bf16(a1, b0, acc[1][0], 0, 0, 0);
            acc[1][1] = __builtin_amdgcn_mfma_f32_16x16x32_bf16(a1, b1, acc[1][1], 0, 0, 0);
        }

        if (step < 15) {   // write prefetched tiles into the other buffer
            #pragma unroll
            for (int p = 0; p < 4; ++p)
                *(short8*)&As[cur ^ 1][p * 32 + arow][acol] = apre[p];
            #pragma unroll
            for (int p = 0; p < 4; ++p) {
                int crow = p * 16 + srow;
                unsigned int raw = spre[p];
                float v0 = __expf(bf2f((unsigned short)(raw & 0xFFFF)) - scm[2 * uq]) * sci[2 * uq];
                float v1 = __expf(bf2f((unsigned short)(raw >> 16)) - scm[2 * uq + 1]) * sci[2 * uq + 1];
                Bs[cur ^ 1][2 * uq][crow]     = (short)f2bf(v0);
                Bs[cur ^ 1][2 * uq + 1][crow] = (short)f2bf(v1);
            }
        }
    }

    #pragma unroll
    for (int fi = 0; fi < 2; ++fi)
        #pragma unroll
        for (int fj = 0; fj < 2; ++fj)
            #pragma unroll
            for (int rr = 0; rr < 4; ++rr) {
                int d = wave * 32 + fi * 16 + quad * 4 + rr;
                int q = q0 + fj * 16 + l15;
                Pbf[((size_t)(b * D_ + d)) * QL_ + q] = f2bf(acc[fi][fj][rr]);
            }
}

// ---------------------------------------------------------------------------
// k_av2: fused AV GEMMs, planes 0..3 in one pass.  T14 schedule: next-step
// global loads issued between the write-barrier and the MFMA cluster, so the
// write phase pays ~zero vmcnt wait.  Single-buffered LDS (keeps 2 blocks/CU).
// ---------------------------------------------------------------------------
__global__ __launch_bounds__(256) void k_av2(const unsigned short* __restrict__ Qbf,
                                             const unsigned short* __restrict__ Pbf,
                                             const unsigned short* __restrict__ Sbf,
                                             const float* __restrict__ rmax,
                                             const float* __restrict__ rinv,
                                             const float* __restrict__ C,
                                             float* __restrict__ out) {
    int b, nt;
    swz_bt(blockIdx.x, b, nt);
    int n0 = nt * 64;

    int tid  = threadIdx.x;
    int lane = tid & 63, wave = tid >> 6;
    int wm = wave >> 1, wn = wave & 1;
    int quad = lane >> 4, l15 = lane & 15;

    __shared__ __align__(16) short AsQ[128][72];
    __shared__ __align__(16) short AsP[128][72];
    __shared__ __align__(16) short Bs[64][72];
    __shared__ float srm[64], sri[64];

    if (tid < 64) {
        srm[tid] = rmax[b * CL_ + n0 + tid];
        sri[tid] = rinv[b * CL_ + n0 + tid];
    }

    const unsigned short* Qb = Qbf + (size_t)b * D_ * QL_;
    const unsigned short* Pb = Pbf + (size_t)b * D_ * QL_;
    const unsigned short* Sb = Sbf + ((size_t)(b * CL_ + n0)) * QL_;

    int arow = tid >> 3;
    int acol = (tid & 7) * 8;
    int brow = tid >> 2;             // 0..63 (c-local row of S1)
    int bcol = (tid & 3) * 16;       // 16 k-elems per thread

    // prologue: issue k0=0 loads
    short8 qa[4], pa[4];
    uint4 sraw[2];
    #pragma unroll
    for (int p = 0; p < 4; ++p) {
        int row = p * 32 + arow;
        qa[p] = *(const short8*)(Qb + (size_t)row * QL_ + acol);
        pa[p] = *(const short8*)(Pb + (size_t)row * QL_ + acol);
    }
    #pragma unroll
    for (int h = 0; h < 2; ++h)
        sraw[h] = *(const uint4*)(Sb + (size_t)brow * QL_ + bcol + h * 8);

    __syncthreads();   // srm/sri visible
    float brm = srm[brow], bri = sri[brow];

    float4v accQ[4][2] = {};
    float4v accP[4][2] = {};

    for (int k0 = 0; k0 < QL_; k0 += 64) {
        // write phase (vmcnt waits only for loads issued one step earlier)
        #pragma unroll
        for (int p = 0; p < 4; ++p) {
            int row = p * 32 + arow;
            *(short8*)&AsQ[row][acol] = qa[p];
            *(short8*)&AsP[row][acol] = pa[p];
        }
        #pragma unroll
        for (int h = 0; h < 2; ++h) {
            unsigned int rw[4] = {sraw[h].x, sraw[h].y, sraw[h].z, sraw[h].w};
            short8 vv;
            #pragma unroll
            for (int j = 0; j < 8; ++j) {
                unsigned short bits = (unsigned short)((rw[j >> 1] >> ((j & 1) * 16)) & 0xFFFF);
                vv[j] = (short)f2bf(__expf(bf2f(bits) - brm) * bri);
            }
            *(short8*)&Bs[brow][bcol + h * 8] = vv;
        }
        __syncthreads();

        if (k0 + 64 < QL_) {   // issue next-step loads; they fly during MFMA
            #pragma unroll
            for (int p = 0; p < 4; ++p) {
                int row = p * 32 + arow;
                qa[p] = *(const short8*)(Qb + (size_t)row * QL_ + k0 + 64 + acol);
                pa[p] = *(const short8*)(Pb + (size_t)row * QL_ + k0 + 64 + acol);
            }
            #pragma unroll
            for (int h = 0; h < 2; ++h)
                sraw[h] = *(const uint4*)(Sb + (size_t)brow * QL_ + k0 + 64 + bcol + h * 8);
        }

        #pragma unroll
        for (int ks = 0; ks < 64; ks += 32) {
            short8 b0 = *(const short8*)&Bs[wn * 32 + l15][ks + quad * 8];
            short8 b1 = *(const short8*)&Bs[wn * 32 + 16 + l15][ks + quad * 8];
            #pragma unroll
            for (int fi = 0; fi < 4; ++fi) {
                short8 aq = *(const short8*)&AsQ[wm * 64 + fi * 16 + l15][ks + quad * 8];
                accQ[fi][0] = __builtin_amdgcn_mfma_f32_16x16x32_bf16(aq, b0, accQ[fi][0], 0, 0, 0);
                accQ[fi][1] = __builtin_amdgcn_mfma_f32_16x16x32_bf16(aq, b1, accQ[fi][1], 0, 0, 0);
            }
            #pragma unroll
            for (int fi = 0; fi < 4; ++fi) {
                short8 ap = *(const short8*)&AsP[wm * 64 + fi * 16 + l15][ks + quad * 8];
                accP[fi][0] = __builtin_amdgcn_mfma_f32_16x16x32_bf16(ap, b0, accP[fi][0], 0, 0, 0);
                accP[fi][1] = __builtin_amdgcn_mfma_f32_16x16x32_bf16(ap, b1, accP[fi][1], 0, 0, 0);
            }
        }
        __syncthreads();
    }

    #pragma unroll
    for (int fi = 0; fi < 4; ++fi)
        #pragma unroll
        for (int fj = 0; fj < 2; ++fj)
            #pragma unroll
            for (int rr = 0; rr < 4; ++rr) {
                int d = wm * 64 + fi * 16 + quad * 4 + rr;
                int c = n0 + wn * 32 + fj * 16 + l15;
                float ct = C[((size_t)(b * D_ + d)) * CL_ + c];
                float vq = accQ[fi][fj][rr];
                float vp = accP[fi][fj][rr];
                size_t ob = ((size_t)(b * 4 * D_ + d)) * CL_ + c;
                out[ob]                        = ct;
                out[ob + (size_t)D_ * CL_]     = vq;
                out[ob + 2 * (size_t)D_ * CL_] = ct * vq;
                out[ob + 3 * (size_t)D_ * CL_] = ct * vp;
            }
}

// ---------------------------------------------------------------------------
// Launch. Workspace (~65 MB): Ubf 8.4, Qtbf 4.2, Qbf 4.2, Cbf 8.4, Pbf 4.2,
// Sbf 33.6, stats ~2.3 MB.
// ---------------------------------------------------------------------------
extern "C" void kernel_launch(void* const* d_in, const int* in_sizes, int n_in,
                              void* d_out, int out_size, void* d_ws, size_t ws_size,
                              hipStream_t stream) {
    const float* C = (const float*)d_in[0];
    const float* Q = (const float*)d_in[1];
    const float* W = (const float*)d_in[2];
    float* out = (float*)d_out;

    unsigned short* Ubf  = (unsigned short*)d_ws;
    unsigned short* Qtbf = Ubf  + (size_t)B_ * CL_ * D_;
    unsigned short* Qbf  = Qtbf + (size_t)B_ * QL_ * D_;
    unsigned short* Cbf  = Qbf  + (size_t)B_ * D_ * QL_;
    unsigned short* Pbf  = Cbf  + (size_t)B_ * D_ * CL_;
    unsigned short* Sbf  = Pbf  + (size_t)B_ * D_ * QL_;
    float* bias  = (float*)(Sbf + (size_t)B_ * CL_ * QL_);
    float* rmax  = bias  + (size_t)B_ * CL_;
    float* rinv  = rmax  + (size_t)B_ * CL_;
    float* pcmax = rinv  + (size_t)B_ * CL_;
    float* pcsum = pcmax + (size_t)B_ * 16 * QL_;

    k_u_bias<<<dim3(CL_ / 32, B_), 256, 0, stream>>>(C, W, Ubf, bias, Cbf);
    k_qt<<<dim3(QL_ / 64, D_ / 64, B_), 256, 0, stream>>>(Q, Qtbf, Qbf);
    k_gs2<<<512, 256, 0, stream>>>(Ubf, Qtbf, bias, Sbf, rmax, rinv, pcmax, pcsum);
    k_gp<<<512, 256, 0, stream>>>(Cbf, Sbf, pcmax, pcsum, Pbf);
    k_av2<<<512, 256, 0, stream>>>(Qbf, Pbf, Sbf, rmax, rinv, C, out);
}